// Round 12
// baseline (373.425 us; speedup 1.0000x reference)
//
#include <hip/hip_runtime.h>

#define NZ 81          // 9x9 zones
#define OBS_DIM 48
#define MAX_ADJ 5
#define NTASK (NZ * MAX_ADJ)   // 405
#define NEG_INF -1000000000.0f
#define BLOCK 512              // MUST be >= NTASK (405): one thread per task
#define ROWS 16
#define ROW_DW (NZ * NZ)       // 6561

// Setup: Wt[d][t] = W[n][d][k] with t = n*5+k. 78 KB, one-time per launch.
__global__ void transpose_w_kernel(const float* __restrict__ W,
                                   float* __restrict__ Wt) {
    const int j = blockIdx.x * 256 + threadIdx.x;   // over 48*405
    if (j < OBS_DIM * NTASK) {
        const int d = j / NTASK;
        const int t = j - d * NTASK;
        const int n = t / MAX_ADJ;
        const int k = t - n * MAX_ADJ;
        Wt[j] = W[n * (OBS_DIM * MAX_ADJ) + d * MAX_ADJ + k];
    }
}

// Main kernel: EXACT round-4 structure (best measured: 177 us, BLOCK=512).
// Single change vs R4: lane-coalesced Wt[d*405+tid] (2 lines/instr) instead
// of the 20B-strided W[n][d][k] gather (~10.5 lines/instr).
template<bool USE_WT>
__global__ __launch_bounds__(BLOCK) void taxi_actor_kernel(
    const float* __restrict__ obs,   // [B, 48]
    const float* __restrict__ W,     // [81, 48, 5]
    const float* __restrict__ Wt,    // [48, 405] transposed (d_ws)
    const float* __restrict__ bias,  // [81, 5]
    const int*   __restrict__ idx,   // [81, 5]
    const float* __restrict__ mask,  // [81, 5]
    float* __restrict__ out)         // [B, 81, 81]
{
    __shared__ float s_obs[ROWS * OBS_DIM];   // 3 KB
    __shared__ float s_logits[NTASK];         // 1.6 KB
    __shared__ int   s_idx[NTASK];            // 1.6 KB (masked -> -1)
    __shared__ float s_tile[ROW_DW];          // 26.2 KB output tile

    const int tid = threadIdx.x;
    const size_t b0 = (size_t)blockIdx.x * ROWS;

    // Stage obs rows (coalesced) + adjacency; zero tile ONCE (scatter
    // positions are row-invariant, values overwritten each row).
    for (int i = tid; i < ROWS * OBS_DIM; i += BLOCK)
        s_obs[i] = obs[b0 * OBS_DIM + i];
    for (int i = tid; i < ROW_DW; i += BLOCK)
        s_tile[i] = 0.0f;
    if (tid < NTASK)
        s_idx[tid] = (mask[tid] > 0.0f) ? idx[tid] : -1;
    __syncthreads();

    // Per-task constants.
    float bv = 0.0f;
    bool valid = false;
    const float* __restrict__ Wp = W;
    if (tid < NTASK) {
        bv = bias[tid];
        valid = (mask[tid] > 0.0f);
        if (!USE_WT) {
            const int n = tid / MAX_ADJ;
            const int k = tid - n * MAX_ADJ;
            Wp = W + n * (OBS_DIM * MAX_ADJ) + k;
        }
    }

    for (int r = 0; r < ROWS; ++r) {
        // Dot: 405 threads, one task each.
        float acc = bv;
        if (tid < NTASK) {
            const float* __restrict__ o = s_obs + r * OBS_DIM;
            if (USE_WT) {
                #pragma unroll
                for (int d = 0; d < OBS_DIM; ++d)
                    acc = fmaf(o[d], Wt[d * NTASK + tid], acc);  // lane-coalesced
            } else {
                #pragma unroll
                for (int d = 0; d < OBS_DIM; ++d)
                    acc = fmaf(o[d], Wp[d * MAX_ADJ], acc);      // strided fallback
            }
        }
        __syncthreads();   // (1) prev row's store done reading s_tile
        if (tid < NTASK)
            s_logits[tid] = valid ? acc : NEG_INF;
        __syncthreads();   // (2) logits visible

        // Softmax + scatter: 81 threads.
        if (tid < NZ) {
            float l[MAX_ADJ], p[MAX_ADJ];
            float m = NEG_INF;
            #pragma unroll
            for (int k = 0; k < MAX_ADJ; ++k) {
                l[k] = s_logits[tid * MAX_ADJ + k];
                m = fmaxf(m, l[k]);
            }
            float s = 0.0f;
            #pragma unroll
            for (int k = 0; k < MAX_ADJ; ++k) {
                p[k] = __expf(l[k] - m);   // masked: exp(-1e9) -> 0
                s += p[k];
            }
            const float inv = 1.0f / s;
            #pragma unroll
            for (int k = 0; k < MAX_ADJ; ++k) {
                const int z = s_idx[tid * MAX_ADJ + k];
                if (z >= 0) s_tile[tid * NZ + z] = p[k] * inv;
            }
        }
        __syncthreads();   // (3) tile ready

        // Coalesced streaming store of the 81x81 tile (proven exact-byte).
        float* __restrict__ outb = out + (b0 + r) * (size_t)ROW_DW;
        for (int i = tid; i < ROW_DW; i += BLOCK)
            outb[i] = s_tile[i];
    }
}

extern "C" void kernel_launch(void* const* d_in, const int* in_sizes, int n_in,
                              void* d_out, int out_size, void* d_ws, size_t ws_size,
                              hipStream_t stream) {
    const float* obs  = (const float*)d_in[0];
    const float* W    = (const float*)d_in[1];
    const float* bias = (const float*)d_in[2];
    const int*   idx  = (const int*)d_in[3];
    const float* mask = (const float*)d_in[4];
    float* out = (float*)d_out;

    const int B = in_sizes[0] / OBS_DIM;   // 32768, divisible by ROWS
    const size_t wt_bytes = (size_t)OBS_DIM * NTASK * sizeof(float);  // 77760

    if (ws_size >= wt_bytes) {
        float* Wt = (float*)d_ws;
        transpose_w_kernel<<<(OBS_DIM * NTASK + 255) / 256, 256, 0, stream>>>(W, Wt);
        taxi_actor_kernel<true><<<B / ROWS, BLOCK, 0, stream>>>(
            obs, W, Wt, bias, idx, mask, out);
    } else {
        taxi_actor_kernel<false><<<B / ROWS, BLOCK, 0, stream>>>(
            obs, W, (const float*)W, bias, idx, mask, out);
    }
}